// Round 9
// baseline (324.006 us; speedup 1.0000x reference)
//
#include <hip/hip_runtime.h>
#include <hip/hip_fp16.h>

#define N_IND 1000000
#define N_ORG 300000
#define N_EXT 100000
#define F 64
#define E_PER 1000000
#define NREL 14

#define BW_IND 1024             // ind bucket width (nodes)
#define BW_ORG 256              // org bucket width (nodes)
#define NB_IND 977              // ceil(N_IND/1024)
#define NB_ORG 1172             // ceil(N_ORG/256)
#define NB_HMAX 1280            // hist/table rows (covers 1172), 5/thread
#define CHUNK 4096              // edges per column
#define COLS_PER_REL 245        // ceil(E_PER/CHUNK)
#define NCOL (NREL * COLS_PER_REL) // 3430
#define LAST_N (E_PER - (COLS_PER_REL - 1) * CHUNK) // 576 (divisible by 4)
#define COLS_PER_TYPE (7 * COLS_PER_REL) // 1715

#define FIX_SCALE 262144.0f            // 2^18
#define FIX_INV   3.814697265625e-6f   // 2^-18

// ---- workspace layout (in 4-byte words; d_ws is 1 GB per harness fill) ----
static const size_t OFF_PAY      = 0;          // u32[NCOL][CHUNK] = 14,049,280
static const size_t OFF_CNTOFF   = 14049280;   // u32[NCOL][NB_HMAX] = 4,390,400
static const size_t OFF_CNTOFF_T = 18439680;   // u32[NB_HMAX][NCOL] = 4,390,400
static const size_t OFF_P_IND    = 22830080;   // fp16[5][N_IND]
static const size_t OFF_P_ORG    = 25330080;   // fp16[5][N_ORG]
static const size_t OFF_P_EXT    = 26080080;   // fp16[4][N_EXT]
static const size_t OFF_BASE_IND = 26280080;   // f32[N_IND]
static const size_t OFF_BASE_ORG = 27280080;   // f32[N_ORG]
static const size_t OFF_WM_IND   = 27580080;   // 6*64
static const size_t OFF_WM_ORG   = 27580464;   // 6*64
static const size_t OFF_WM_EXT   = 27580848;   // 4*64
static const size_t OFF_BSUM     = 27581104;   // 2
// total ~27.58M words = 110.3 MB

__global__ void prep_kernel(const float* __restrict__ Wl,
                            const float* __restrict__ Wr,
                            const float* __restrict__ b,
                            float* __restrict__ wm_ind,
                            float* __restrict__ wm_org,
                            float* __restrict__ wm_ext,
                            float* __restrict__ bsum) {
    int t = threadIdx.x; // 64 threads
    const int ind_wl[5] = {0, 3, 6, 7, 10};
    const int org_wl[5] = {1, 4, 8, 11, 13};
    const int ext_wl[4] = {2, 5, 9, 12};
    const int ind_r[7]  = {0, 1, 2, 7, 8, 9, 13};
    const int org_r[7]  = {3, 4, 5, 6, 10, 11, 12};
#pragma unroll
    for (int k = 0; k < 5; ++k) wm_ind[k * 64 + t] = Wl[ind_wl[k] * 64 + t];
#pragma unroll
    for (int k = 0; k < 5; ++k) wm_org[k * 64 + t] = Wl[org_wl[k] * 64 + t];
#pragma unroll
    for (int k = 0; k < 4; ++k) wm_ext[k * 64 + t] = Wl[ext_wl[k] * 64 + t];
    float si = 0.f, so = 0.f;
#pragma unroll
    for (int k = 0; k < 7; ++k) {
        si += Wr[ind_r[k] * 64 + t];
        so += Wr[org_r[k] * 64 + t];
    }
    wm_ind[5 * 64 + t] = si;
    wm_org[5 * 64 + t] = so;
    if (t == 0) {
        float bi = 0.f, bo = 0.f;
#pragma unroll
        for (int k = 0; k < 7; ++k) { bi += b[ind_r[k]]; bo += b[org_r[k]]; }
        bsum[0] = bi;
        bsum[1] = bo;
    }
}

// Rank-1 projections -> fp16 p slices (+ f32 base for dst types).
template <int K, bool HASBASE>
__global__ __launch_bounds__(256) void proj_kernel(
    const float* __restrict__ x, int n,
    const float* __restrict__ wm,
    __half* __restrict__ p,
    float* __restrict__ base_out,
    const float* __restrict__ bsum) {
    int i = blockIdx.x * 256 + threadIdx.x;
    if (i >= n) return;
    const float4* xv = (const float4*)(x + (size_t)i * F);
    float acc[K];
#pragma unroll
    for (int k = 0; k < K; ++k) acc[k] = 0.f;
#pragma unroll
    for (int c = 0; c < 16; ++c) {
        float4 v = xv[c];
#pragma unroll
        for (int k = 0; k < K; ++k) {
            const float* w = wm + k * 64 + c * 4;
            acc[k] += v.x * w[0] + v.y * w[1] + v.z * w[2] + v.w * w[3];
        }
    }
    constexpr int NP = HASBASE ? K - 1 : K;
#pragma unroll
    for (int k = 0; k < NP; ++k) p[(size_t)k * n + i] = __float2half_rn(acc[k]);
    if (HASBASE) base_out[i] = acc[K - 1] + bsum[0];
}

// Scatter v5: grid = 3430 (first 1715 blocks = ind-dst cols, rest org-dst).
// Per-type bucket shift (ind:10, org:8). dst kept in VGPRs across passes,
// uint4 stream-out. LDS = 16K stage + 5K hist ~= 21.5 KB.
__global__ __launch_bounds__(256, 7) void scatter_kernel(
    const int* __restrict__ ei,
    const unsigned short* __restrict__ p_ind,
    const unsigned short* __restrict__ p_org,
    const unsigned short* __restrict__ p_ext,
    unsigned* __restrict__ pay,      // [NCOL][CHUNK]
    unsigned* __restrict__ cntoff) { // [NCOL][NB_HMAX]
    const int srcType[NREL] = {0,1,2,0,1,2,0,0,1,2,0,1,2,1};
    const int srcSlot[NREL] = {0,0,0,1,1,1,2,3,2,2,4,3,3,4};
    const int dstSlot[NREL] = {0,1,2,0,1,2,3,3,4,5,4,5,6,6};
    const int relsI[7] = {0, 1, 2, 7, 8, 9, 13};
    const int relsO[7] = {3, 4, 5, 6, 10, 11, 12};

    __shared__ unsigned h[NB_HMAX];  // histogram, then cursor (reused)
    __shared__ unsigned stage[CHUNK];
    __shared__ unsigned wsum[4];

    const int t = threadIdx.x;
    const int lane = t & 63, wv = t >> 6;

    const bool isOrg = blockIdx.x >= COLS_PER_TYPE;
    const int j0 = blockIdx.x - (isOrg ? COLS_PER_TYPE : 0);
    const int rl = j0 / COLS_PER_REL;
    const int i = j0 - rl * COLS_PER_REL;
    const int r = (isOrg ? relsO : relsI)[rl];
    const int shift = isOrg ? 8 : 10;
    const unsigned lmask = (1u << shift) - 1u;
    const int cid = r * COLS_PER_REL + i;
    const int n = (i == COLS_PER_REL - 1) ? LAST_N : CHUNK;
    const int n4 = n >> 2;
    const int* srcp = ei + ((size_t)r * 2 + 0) * E_PER + (size_t)i * CHUNK;
    const int* dstp = ei + ((size_t)r * 2 + 1) * E_PER + (size_t)i * CHUNK;
    const unsigned slotbits = (unsigned)dstSlot[r] << shift;
    const int st = srcType[r];
    const unsigned short* psrc =
        (st == 0) ? p_ind + (size_t)srcSlot[r] * N_IND :
        (st == 1) ? p_org + (size_t)srcSlot[r] * N_ORG :
                    p_ext + (size_t)srcSlot[r] * N_EXT;

    // pass 1: histogram; keep dst values in registers for pass 2
#pragma unroll
    for (int j = 0; j < 5; ++j) h[t * 5 + j] = 0u;
    __syncthreads();
    const int4* dst4 = (const int4*)dstp;
    int4 dreg[4];
#pragma unroll
    for (int u = 0; u < 4; ++u) {
        int k = t + u * 256;
        if (k < n4) {
            int4 d = dst4[k];
            dreg[u] = d;
            atomicAdd(&h[d.x >> shift], 1u);
            atomicAdd(&h[d.y >> shift], 1u);
            atomicAdd(&h[d.z >> shift], 1u);
            atomicAdd(&h[d.w >> shift], 1u);
        }
    }
    __syncthreads();

    // exclusive scan over 1280 counters: 5/thread + shfl wave scan.
    unsigned loc[5], s0 = 0;
#pragma unroll
    for (int j = 0; j < 5; ++j) { loc[j] = h[t * 5 + j]; s0 += loc[j]; }
    unsigned x = s0;
#pragma unroll
    for (int d = 1; d < 64; d <<= 1) {
        unsigned v = __shfl_up(x, d, 64);
        if (lane >= d) x += v;
    }
    if (lane == 63) wsum[wv] = x;
    __syncthreads();
    unsigned base = x - s0;
    for (int j = 0; j < wv; ++j) base += wsum[j];
    unsigned* co = cntoff + (size_t)cid * NB_HMAX;
#pragma unroll
    for (int j = 0; j < 5; ++j) {
        co[t * 5 + j] = (base << 16) | loc[j];
        h[t * 5 + j] = base;   // cursor seed (own slot only)
        base += loc[j];
    }
    __syncthreads();

    // pass 2: gather p, place into LDS stage at sorted positions
    const int4* src4 = (const int4*)srcp;
#pragma unroll
    for (int u = 0; u < 4; ++u) {
        int k = t + u * 256;
        if (k < n4) {
            int4 s = src4[k];
            int4 d = dreg[u];
#pragma unroll
            for (int q = 0; q < 4; ++q) {
                int src = (q == 0) ? s.x : (q == 1) ? s.y : (q == 2) ? s.z : s.w;
                int dst = (q == 0) ? d.x : (q == 1) ? d.y : (q == 2) ? d.z : d.w;
                unsigned pvbits = psrc[src];
                unsigned word = (pvbits << 16) | slotbits | ((unsigned)dst & lmask);
                unsigned pos = atomicAdd(&h[dst >> shift], 1u);
                stage[pos] = word;
            }
        }
    }
    __syncthreads();

    // dense stream-out, 16 B/lane
    uint4* payc4 = (uint4*)(pay + (size_t)cid * CHUNK);
    const uint4* st4 = (const uint4*)stage;
    for (int k = t; k < n4; k += 256) payc4[k] = st4[k];
}

// Transpose cntoff [NCOL][NB_HMAX] -> [NB_HMAX][NCOL] (32x32 tiles).
__global__ __launch_bounds__(256) void transpose_kernel(
    const unsigned* __restrict__ in, unsigned* __restrict__ out) {
    __shared__ unsigned tb[32][33];
    const int c0 = blockIdx.x * 32; // col in 'in' (bucket row idx)
    const int r0 = blockIdx.y * 32; // row in 'in' (cid)
    const int tx = threadIdx.x & 31, ty = threadIdx.x >> 5;
#pragma unroll
    for (int j = 0; j < 32; j += 8) {
        int r = r0 + ty + j, c = c0 + tx;
        if (r < NCOL && c < NB_HMAX) tb[ty + j][tx] = in[(size_t)r * NB_HMAX + c];
    }
    __syncthreads();
#pragma unroll
    for (int j = 0; j < 32; j += 8) {
        int r = c0 + ty + j, c = r0 + tx;
        if (r < NB_HMAX && c < NCOL) out[(size_t)r * NCOL + c] = tb[tx][ty + j];
    }
}

// One block per (type, bucket). ISORG=false: BW=1024 (28 KB LDS);
// ISORG=true: BW=256 (7 KB LDS). Packed fixed-point LDS accumulate,
// fused finalize + sigmoid.
template <bool ISORG>
__global__ __launch_bounds__(256) void gather_kernel(
    const unsigned* __restrict__ pay,
    const unsigned* __restrict__ cntoffT,
    const float* __restrict__ base,
    float* __restrict__ outp) {
    constexpr int BWt = ISORG ? BW_ORG : BW_IND;
    constexpr int shift = ISORG ? 8 : 10;
    constexpr int nn = ISORG ? N_ORG : N_IND;
    __shared__ unsigned acc[7 * BWt];
    const int b = blockIdx.x;
    const int t = threadIdx.x;
    for (int j = t; j < 7 * BWt; j += 256) acc[j] = 0u;
    __syncthreads();

    const int relsI[7] = {0, 1, 2, 7, 8, 9, 13};
    const int relsO[7] = {3, 4, 5, 6, 10, 11, 12};
    const unsigned* row = cntoffT + (size_t)b * NCOL;
    for (int j = t; j < COLS_PER_TYPE; j += 256) {
        int rl = j / COLS_PER_REL;
        int c = j - rl * COLS_PER_REL;
        int cid = (ISORG ? relsO[rl] : relsI[rl]) * COLS_PER_REL + c;
        unsigned co = row[cid];
        unsigned cnt = co & 0xffffu;
        if (!cnt) continue;
        const unsigned* seg = pay + (size_t)cid * CHUNK + (co >> 16);
        for (unsigned e = 0; e < cnt; ++e) {
            unsigned w = seg[e];
            unsigned short hs = (unsigned short)(w >> 16);
            __half hh;
            __builtin_memcpy(&hh, &hs, 2);
            float pv = __half2float(hh);
            int fixed = (int)rintf(pv * FIX_SCALE);
            unsigned contrib = (1u << 26) + (unsigned)fixed;
            atomicAdd(&acc[((w >> shift) & 7u) * BWt + (w & (BWt - 1))], contrib);
        }
    }
    __syncthreads();

    for (int loc = t; loc < BWt; loc += 256) {
        int g = b * BWt + loc;
        if (g < nn) {
            float a = base[g];
#pragma unroll
            for (int k = 0; k < 7; ++k) {
                unsigned w = acc[k * BWt + loc];
                int s26 = ((int)(w << 6)) >> 6;         // sign-extend low 26
                unsigned c = (w - (unsigned)s26) >> 26; // exact count
                a += (float)s26 * FIX_INV / fmaxf((float)c, 1.0f);
            }
            outp[g] = 1.0f / (1.0f + __expf(-a));
        }
    }
}

extern "C" void kernel_launch(void* const* d_in, const int* in_sizes, int n_in,
                              void* d_out, int out_size, void* d_ws, size_t ws_size,
                              hipStream_t stream) {
    const float* x_ind = (const float*)d_in[0];
    const float* x_org = (const float*)d_in[1];
    const float* x_ext = (const float*)d_in[2];
    const float* Wl    = (const float*)d_in[3];
    const float* Wr    = (const float*)d_in[4];
    const float* b     = (const float*)d_in[5];
    const int*   ei    = (const int*)d_in[6];
    float* out = (float*)d_out;

    float* ws = (float*)d_ws;
    unsigned* pay      = (unsigned*)(ws + OFF_PAY);
    unsigned* cntoff   = (unsigned*)(ws + OFF_CNTOFF);
    unsigned* cntoffT  = (unsigned*)(ws + OFF_CNTOFF_T);
    __half* p_ind      = (__half*)(ws + OFF_P_IND);
    __half* p_org      = (__half*)(ws + OFF_P_ORG);
    __half* p_ext      = (__half*)(ws + OFF_P_EXT);
    float* base_ind    = ws + OFF_BASE_IND;
    float* base_org    = ws + OFF_BASE_ORG;
    float* wm_ind      = ws + OFF_WM_IND;
    float* wm_org      = ws + OFF_WM_ORG;
    float* wm_ext      = ws + OFF_WM_EXT;
    float* bsum        = ws + OFF_BSUM;

    prep_kernel<<<1, 64, 0, stream>>>(Wl, Wr, b, wm_ind, wm_org, wm_ext, bsum);

    proj_kernel<6, true><<<(N_IND + 255) / 256, 256, 0, stream>>>(
        x_ind, N_IND, wm_ind, p_ind, base_ind, bsum + 0);
    proj_kernel<6, true><<<(N_ORG + 255) / 256, 256, 0, stream>>>(
        x_org, N_ORG, wm_org, p_org, base_org, bsum + 1);
    proj_kernel<4, false><<<(N_EXT + 255) / 256, 256, 0, stream>>>(
        x_ext, N_EXT, wm_ext, p_ext, nullptr, bsum);

    scatter_kernel<<<2 * COLS_PER_TYPE, 256, 0, stream>>>(
        ei, (const unsigned short*)p_ind, (const unsigned short*)p_org,
        (const unsigned short*)p_ext, pay, cntoff);

    dim3 tgrid(NB_HMAX / 32, (NCOL + 31) / 32);
    transpose_kernel<<<tgrid, 256, 0, stream>>>(cntoff, cntoffT);

    gather_kernel<false><<<NB_IND, 256, 0, stream>>>(pay, cntoffT, base_ind, out);
    gather_kernel<true><<<NB_ORG, 256, 0, stream>>>(pay, cntoffT, base_org, out + N_IND);
}

// Round 10
// 265.879 us; speedup vs baseline: 1.2186x; 1.2186x over previous
//
#include <hip/hip_runtime.h>
#include <hip/hip_fp16.h>

#define N_IND 1000000
#define N_ORG 300000
#define N_EXT 100000
#define F 64
#define E_PER 1000000
#define NREL 14

#define BW 1024                 // bucket width (nodes), both dst types
#define NB_IND 977              // ceil(N_IND/1024)
#define NB_ORG 293              // ceil(N_ORG/1024)
#define NBKT 1270
#define NB_H 1024               // hist entries (covers 977)
#define CHUNK 8192              // edges per column
#define COLS_PER_REL 123        // ceil(E_PER/CHUNK)
#define NCOL (NREL * COLS_PER_REL) // 1722
#define LAST_N (E_PER - (COLS_PER_REL - 1) * CHUNK) // 576 (divisible by 4)
#define COLS_PER_TYPE (7 * COLS_PER_REL) // 861
#define TSCAT 512

#define FIX_SCALE 262144.0f            // 2^18
#define FIX_INV   3.814697265625e-6f   // 2^-18

// ---- workspace layout (in 4-byte words) ----
static const size_t OFF_PAY      = 0;          // u32[1722][8192] = 14,106,624
static const size_t OFF_CNTOFF   = 14106624;   // u32[1722][1024] = 1,763,328
static const size_t OFF_CNTOFF_T = 15869952;   // u32[1024][1722] = 1,763,328
static const size_t OFF_P_IND    = 17633280;   // fp16[5][N_IND]
static const size_t OFF_P_ORG    = 20133280;   // fp16[5][N_ORG]
static const size_t OFF_P_EXT    = 20883280;   // fp16[4][N_EXT]
static const size_t OFF_BASE_IND = 21083280;   // f32[N_IND]
static const size_t OFF_BASE_ORG = 22083280;   // f32[N_ORG]
static const size_t OFF_WM_IND   = 22383280;   // 6*64
static const size_t OFF_WM_ORG   = 22383664;   // 6*64
static const size_t OFF_WM_EXT   = 22384048;   // 4*64
static const size_t OFF_BSUM     = 22384304;   // 2
// total ~22.38M words = 89.5 MB

__global__ void prep_kernel(const float* __restrict__ Wl,
                            const float* __restrict__ Wr,
                            const float* __restrict__ b,
                            float* __restrict__ wm_ind,
                            float* __restrict__ wm_org,
                            float* __restrict__ wm_ext,
                            float* __restrict__ bsum) {
    int t = threadIdx.x; // 64 threads
    const int ind_wl[5] = {0, 3, 6, 7, 10};
    const int org_wl[5] = {1, 4, 8, 11, 13};
    const int ext_wl[4] = {2, 5, 9, 12};
    const int ind_r[7]  = {0, 1, 2, 7, 8, 9, 13};
    const int org_r[7]  = {3, 4, 5, 6, 10, 11, 12};
#pragma unroll
    for (int k = 0; k < 5; ++k) wm_ind[k * 64 + t] = Wl[ind_wl[k] * 64 + t];
#pragma unroll
    for (int k = 0; k < 5; ++k) wm_org[k * 64 + t] = Wl[org_wl[k] * 64 + t];
#pragma unroll
    for (int k = 0; k < 4; ++k) wm_ext[k * 64 + t] = Wl[ext_wl[k] * 64 + t];
    float si = 0.f, so = 0.f;
#pragma unroll
    for (int k = 0; k < 7; ++k) {
        si += Wr[ind_r[k] * 64 + t];
        so += Wr[org_r[k] * 64 + t];
    }
    wm_ind[5 * 64 + t] = si;
    wm_org[5 * 64 + t] = so;
    if (t == 0) {
        float bi = 0.f, bo = 0.f;
#pragma unroll
        for (int k = 0; k < 7; ++k) { bi += b[ind_r[k]]; bo += b[org_r[k]]; }
        bsum[0] = bi;
        bsum[1] = bo;
    }
}

// Rank-1 projections -> fp16 p slices (+ f32 base for dst types).
template <int K, bool HASBASE>
__global__ __launch_bounds__(256) void proj_kernel(
    const float* __restrict__ x, int n,
    const float* __restrict__ wm,
    __half* __restrict__ p,
    float* __restrict__ base_out,
    const float* __restrict__ bsum) {
    int i = blockIdx.x * 256 + threadIdx.x;
    if (i >= n) return;
    const float4* xv = (const float4*)(x + (size_t)i * F);
    float acc[K];
#pragma unroll
    for (int k = 0; k < K; ++k) acc[k] = 0.f;
#pragma unroll
    for (int c = 0; c < 16; ++c) {
        float4 v = xv[c];
#pragma unroll
        for (int k = 0; k < K; ++k) {
            const float* w = wm + k * 64 + c * 4;
            acc[k] += v.x * w[0] + v.y * w[1] + v.z * w[2] + v.w * w[3];
        }
    }
    constexpr int NP = HASBASE ? K - 1 : K;
#pragma unroll
    for (int k = 0; k < NP; ++k) p[(size_t)k * n + i] = __float2half_rn(acc[k]);
    if (HASBASE) base_out[i] = acc[K - 1] + bsum[0];
}

// Scatter v6: 512 threads, CHUNK=8192. LDS = 32K stage + 4K hist = 36 KB ->
// 4 blocks/CU x 8 waves = 32 waves/CU (max occupancy). dst kept in VGPRs
// across passes; uint4 stream-out.
__global__ __launch_bounds__(TSCAT, 8) void scatter_kernel(
    const int* __restrict__ ei,
    const unsigned short* __restrict__ p_ind,
    const unsigned short* __restrict__ p_org,
    const unsigned short* __restrict__ p_ext,
    unsigned* __restrict__ pay,      // [NCOL][CHUNK]
    unsigned* __restrict__ cntoff) { // [NCOL][NB_H]
    const int srcType[NREL] = {0,1,2,0,1,2,0,0,1,2,0,1,2,1};
    const int srcSlot[NREL] = {0,0,0,1,1,1,2,3,2,2,4,3,3,4};
    const int dstSlot[NREL] = {0,1,2,0,1,2,3,3,4,5,4,5,6,6};

    __shared__ unsigned h[NB_H];     // histogram, then cursor (reused)
    __shared__ unsigned stage[CHUNK];
    __shared__ unsigned wsum[8];

    const int t = threadIdx.x;
    const int lane = t & 63, wv = t >> 6; // wv 0..7

    const int cid = blockIdx.x;
    const int r = cid / COLS_PER_REL;
    const int i = cid - r * COLS_PER_REL;
    const int n = (i == COLS_PER_REL - 1) ? LAST_N : CHUNK;
    const int n4 = n >> 2;
    const int* srcp = ei + ((size_t)r * 2 + 0) * E_PER + (size_t)i * CHUNK;
    const int* dstp = ei + ((size_t)r * 2 + 1) * E_PER + (size_t)i * CHUNK;
    const unsigned slotbits = (unsigned)dstSlot[r] << 10;
    const int st = srcType[r];
    const unsigned short* psrc =
        (st == 0) ? p_ind + (size_t)srcSlot[r] * N_IND :
        (st == 1) ? p_org + (size_t)srcSlot[r] * N_ORG :
                    p_ext + (size_t)srcSlot[r] * N_EXT;

    // pass 1: histogram; keep dst values in registers for pass 2
    h[t * 2 + 0] = 0u;
    h[t * 2 + 1] = 0u;
    __syncthreads();
    const int4* dst4 = (const int4*)dstp;
    int4 dreg[4];
#pragma unroll
    for (int u = 0; u < 4; ++u) {
        int k = t + u * TSCAT;
        if (k < n4) {
            int4 d = dst4[k];
            dreg[u] = d;
            atomicAdd(&h[d.x >> 10], 1u);
            atomicAdd(&h[d.y >> 10], 1u);
            atomicAdd(&h[d.z >> 10], 1u);
            atomicAdd(&h[d.w >> 10], 1u);
        }
    }
    __syncthreads();

    // exclusive scan over 1024 counters: 2/thread + shfl wave scan.
    unsigned loc0 = h[t * 2 + 0], loc1 = h[t * 2 + 1];
    unsigned s0 = loc0 + loc1;
    unsigned x = s0;
#pragma unroll
    for (int d = 1; d < 64; d <<= 1) {
        unsigned v = __shfl_up(x, d, 64);
        if (lane >= d) x += v;
    }
    if (lane == 63) wsum[wv] = x;
    __syncthreads();
    unsigned base = x - s0;
    for (int j = 0; j < wv; ++j) base += wsum[j];
    unsigned* co = cntoff + (size_t)cid * NB_H;
    co[t * 2 + 0] = (base << 16) | loc0;
    h[t * 2 + 0] = base;          // cursor seed (own slot only)
    base += loc0;
    co[t * 2 + 1] = (base << 16) | loc1;
    h[t * 2 + 1] = base;
    __syncthreads();

    // pass 2: gather p, place into LDS stage at sorted positions
    const int4* src4 = (const int4*)srcp;
#pragma unroll
    for (int u = 0; u < 4; ++u) {
        int k = t + u * TSCAT;
        if (k < n4) {
            int4 s = src4[k];
            int4 d = dreg[u];
#pragma unroll
            for (int q = 0; q < 4; ++q) {
                int src = (q == 0) ? s.x : (q == 1) ? s.y : (q == 2) ? s.z : s.w;
                int dst = (q == 0) ? d.x : (q == 1) ? d.y : (q == 2) ? d.z : d.w;
                unsigned pvbits = psrc[src];
                unsigned word = (pvbits << 16) | slotbits | ((unsigned)dst & (BW - 1));
                unsigned pos = atomicAdd(&h[dst >> 10], 1u);
                stage[pos] = word;
            }
        }
    }
    __syncthreads();

    // dense stream-out, 16 B/lane
    uint4* payc4 = (uint4*)(pay + (size_t)cid * CHUNK);
    const uint4* st4 = (const uint4*)stage;
    for (int k = t; k < n4; k += TSCAT) payc4[k] = st4[k];
}

// Transpose cntoff [NCOL][NB_H] -> [NB_H][NCOL] (32x32 tiles).
__global__ __launch_bounds__(256) void transpose_kernel(
    const unsigned* __restrict__ in, unsigned* __restrict__ out) {
    __shared__ unsigned tb[32][33];
    const int c0 = blockIdx.x * 32; // bucket idx
    const int r0 = blockIdx.y * 32; // cid
    const int tx = threadIdx.x & 31, ty = threadIdx.x >> 5;
#pragma unroll
    for (int j = 0; j < 32; j += 8) {
        int r = r0 + ty + j, c = c0 + tx;
        if (r < NCOL && c < NB_H) tb[ty + j][tx] = in[(size_t)r * NB_H + c];
    }
    __syncthreads();
#pragma unroll
    for (int j = 0; j < 32; j += 8) {
        int r = c0 + ty + j, c = r0 + tx;
        if (r < NB_H && c < NCOL) out[(size_t)r * NCOL + c] = tb[tx][ty + j];
    }
}

// Single gather: grid = NBKT, org blocks FIRST (3.3x heavier -> no tail).
// One block per (type, bucket): packed fixed-point LDS accumulate over the
// 861 columns of this dst type, fused finalize + sigmoid.
__global__ __launch_bounds__(256) void gather_kernel(
    const unsigned* __restrict__ pay,
    const unsigned* __restrict__ cntoffT,
    const float* __restrict__ base_ind,
    const float* __restrict__ base_org,
    float* __restrict__ out) {
    __shared__ unsigned acc[7 * BW];
    const int blk = blockIdx.x; // 0..292 org, 293..1269 ind
    const int t = threadIdx.x;
    for (int j = t; j < 7 * BW; j += 256) acc[j] = 0u;
    __syncthreads();

    const bool isOrg = blk < NB_ORG;
    const int b = isOrg ? blk : blk - NB_ORG;
    const int relsI[7] = {0, 1, 2, 7, 8, 9, 13};
    const int relsO[7] = {3, 4, 5, 6, 10, 11, 12};

    const unsigned* row = cntoffT + (size_t)b * NCOL;
    for (int j = t; j < COLS_PER_TYPE; j += 256) {
        int rl = j / COLS_PER_REL;
        int c = j - rl * COLS_PER_REL;
        int cid = (isOrg ? relsO[rl] : relsI[rl]) * COLS_PER_REL + c;
        unsigned co = row[cid];
        unsigned cnt = co & 0xffffu;
        if (!cnt) continue;
        const unsigned* seg = pay + (size_t)cid * CHUNK + (co >> 16);
        for (unsigned e = 0; e < cnt; ++e) {
            unsigned w = seg[e];
            unsigned short hs = (unsigned short)(w >> 16);
            __half hh;
            __builtin_memcpy(&hh, &hs, 2);
            float pv = __half2float(hh);
            int fixed = (int)rintf(pv * FIX_SCALE);
            unsigned contrib = (1u << 26) + (unsigned)fixed;
            atomicAdd(&acc[((w >> 10) & 7u) * BW + (w & (BW - 1))], contrib);
        }
    }
    __syncthreads();

    const int nn = isOrg ? N_ORG : N_IND;
    const float* basep = isOrg ? base_org : base_ind;
    float* outp = isOrg ? out + N_IND : out;
    for (int loc = t; loc < BW; loc += 256) {
        int g = b * BW + loc;
        if (g < nn) {
            float a = basep[g];
#pragma unroll
            for (int k = 0; k < 7; ++k) {
                unsigned w = acc[k * BW + loc];
                int s26 = ((int)(w << 6)) >> 6;         // sign-extend low 26
                unsigned c = (w - (unsigned)s26) >> 26; // exact count
                a += (float)s26 * FIX_INV / fmaxf((float)c, 1.0f);
            }
            outp[g] = 1.0f / (1.0f + __expf(-a));
        }
    }
}

extern "C" void kernel_launch(void* const* d_in, const int* in_sizes, int n_in,
                              void* d_out, int out_size, void* d_ws, size_t ws_size,
                              hipStream_t stream) {
    const float* x_ind = (const float*)d_in[0];
    const float* x_org = (const float*)d_in[1];
    const float* x_ext = (const float*)d_in[2];
    const float* Wl    = (const float*)d_in[3];
    const float* Wr    = (const float*)d_in[4];
    const float* b     = (const float*)d_in[5];
    const int*   ei    = (const int*)d_in[6];
    float* out = (float*)d_out;

    float* ws = (float*)d_ws;
    unsigned* pay      = (unsigned*)(ws + OFF_PAY);
    unsigned* cntoff   = (unsigned*)(ws + OFF_CNTOFF);
    unsigned* cntoffT  = (unsigned*)(ws + OFF_CNTOFF_T);
    __half* p_ind      = (__half*)(ws + OFF_P_IND);
    __half* p_org      = (__half*)(ws + OFF_P_ORG);
    __half* p_ext      = (__half*)(ws + OFF_P_EXT);
    float* base_ind    = ws + OFF_BASE_IND;
    float* base_org    = ws + OFF_BASE_ORG;
    float* wm_ind      = ws + OFF_WM_IND;
    float* wm_org      = ws + OFF_WM_ORG;
    float* wm_ext      = ws + OFF_WM_EXT;
    float* bsum        = ws + OFF_BSUM;

    prep_kernel<<<1, 64, 0, stream>>>(Wl, Wr, b, wm_ind, wm_org, wm_ext, bsum);

    proj_kernel<6, true><<<(N_IND + 255) / 256, 256, 0, stream>>>(
        x_ind, N_IND, wm_ind, p_ind, base_ind, bsum + 0);
    proj_kernel<6, true><<<(N_ORG + 255) / 256, 256, 0, stream>>>(
        x_org, N_ORG, wm_org, p_org, base_org, bsum + 1);
    proj_kernel<4, false><<<(N_EXT + 255) / 256, 256, 0, stream>>>(
        x_ext, N_EXT, wm_ext, p_ext, nullptr, bsum);

    scatter_kernel<<<NCOL, TSCAT, 0, stream>>>(
        ei, (const unsigned short*)p_ind, (const unsigned short*)p_org,
        (const unsigned short*)p_ext, pay, cntoff);

    dim3 tgrid(NB_H / 32, (NCOL + 31) / 32);
    transpose_kernel<<<tgrid, 256, 0, stream>>>(cntoff, cntoffT);

    gather_kernel<<<NBKT, 256, 0, stream>>>(pay, cntoffT, base_ind, base_org, out);
}

// Round 11
// 263.175 us; speedup vs baseline: 1.2311x; 1.0103x over previous
//
#include <hip/hip_runtime.h>
#include <hip/hip_fp16.h>

#define N_IND 1000000
#define N_ORG 300000
#define N_EXT 100000
#define F 64
#define E_PER 1000000
#define NREL 14

#define BW 1024                 // bucket width (nodes), both dst types
#define NB_IND 977              // ceil(N_IND/1024)
#define NB_ORG 293              // ceil(N_ORG/1024)
#define NBKT 1270
#define NB_H 1024               // hist entries (covers 977), 1/thread at 1024 thr
#define CHUNK 16384             // edges per column
#define COLS_PER_REL 62         // ceil(E_PER/CHUNK)
#define NCOL (NREL * COLS_PER_REL) // 868
#define LAST_N (E_PER - (COLS_PER_REL - 1) * CHUNK) // 576 (divisible by 4)
#define COLS_PER_TYPE (7 * COLS_PER_REL) // 434
#define TSCAT 1024

#define FIX_SCALE 262144.0f            // 2^18
#define FIX_INV   3.814697265625e-6f   // 2^-18

// ---- workspace layout (in 4-byte words) ----
static const size_t OFF_PAY      = 0;          // u32[868][16384] = 14,221,312
static const size_t OFF_CNTOFF   = 14221312;   // u32[868][1024] = 888,832
static const size_t OFF_CNTOFF_T = 15110144;   // u32[1024][868] = 888,832
static const size_t OFF_P_IND    = 15998976;   // fp16[5][N_IND]
static const size_t OFF_P_ORG    = 18498976;   // fp16[5][N_ORG]
static const size_t OFF_P_EXT    = 19248976;   // fp16[4][N_EXT]
static const size_t OFF_BASE_IND = 19448976;   // f32[N_IND]
static const size_t OFF_BASE_ORG = 20448976;   // f32[N_ORG]
static const size_t OFF_WM_IND   = 20748976;   // 6*64
static const size_t OFF_WM_ORG   = 20749360;   // 6*64
static const size_t OFF_WM_EXT   = 20749744;   // 4*64
static const size_t OFF_BSUM     = 20750000;   // 2
// total ~20.75M words = 83 MB

__global__ void prep_kernel(const float* __restrict__ Wl,
                            const float* __restrict__ Wr,
                            const float* __restrict__ b,
                            float* __restrict__ wm_ind,
                            float* __restrict__ wm_org,
                            float* __restrict__ wm_ext,
                            float* __restrict__ bsum) {
    int t = threadIdx.x; // 64 threads
    const int ind_wl[5] = {0, 3, 6, 7, 10};
    const int org_wl[5] = {1, 4, 8, 11, 13};
    const int ext_wl[4] = {2, 5, 9, 12};
    const int ind_r[7]  = {0, 1, 2, 7, 8, 9, 13};
    const int org_r[7]  = {3, 4, 5, 6, 10, 11, 12};
#pragma unroll
    for (int k = 0; k < 5; ++k) wm_ind[k * 64 + t] = Wl[ind_wl[k] * 64 + t];
#pragma unroll
    for (int k = 0; k < 5; ++k) wm_org[k * 64 + t] = Wl[org_wl[k] * 64 + t];
#pragma unroll
    for (int k = 0; k < 4; ++k) wm_ext[k * 64 + t] = Wl[ext_wl[k] * 64 + t];
    float si = 0.f, so = 0.f;
#pragma unroll
    for (int k = 0; k < 7; ++k) {
        si += Wr[ind_r[k] * 64 + t];
        so += Wr[org_r[k] * 64 + t];
    }
    wm_ind[5 * 64 + t] = si;
    wm_org[5 * 64 + t] = so;
    if (t == 0) {
        float bi = 0.f, bo = 0.f;
#pragma unroll
        for (int k = 0; k < 7; ++k) { bi += b[ind_r[k]]; bo += b[org_r[k]]; }
        bsum[0] = bi;
        bsum[1] = bo;
    }
}

// Rank-1 projections -> fp16 p slices (+ f32 base for dst types).
template <int K, bool HASBASE>
__global__ __launch_bounds__(256) void proj_kernel(
    const float* __restrict__ x, int n,
    const float* __restrict__ wm,
    __half* __restrict__ p,
    float* __restrict__ base_out,
    const float* __restrict__ bsum) {
    int i = blockIdx.x * 256 + threadIdx.x;
    if (i >= n) return;
    const float4* xv = (const float4*)(x + (size_t)i * F);
    float acc[K];
#pragma unroll
    for (int k = 0; k < K; ++k) acc[k] = 0.f;
#pragma unroll
    for (int c = 0; c < 16; ++c) {
        float4 v = xv[c];
#pragma unroll
        for (int k = 0; k < K; ++k) {
            const float* w = wm + k * 64 + c * 4;
            acc[k] += v.x * w[0] + v.y * w[1] + v.z * w[2] + v.w * w[3];
        }
    }
    constexpr int NP = HASBASE ? K - 1 : K;
#pragma unroll
    for (int k = 0; k < NP; ++k) p[(size_t)k * n + i] = __float2half_rn(acc[k]);
    if (HASBASE) base_out[i] = acc[K - 1] + bsum[0];
}

// Scatter v7: 1024 threads, CHUNK=16384. LDS = 64K stage + 4K hist = 68 KB
// -> 2 blocks/CU x 16 waves = 32 waves/CU (max). dst kept in VGPRs across
// passes; uint4 stream-out; 1 hist counter per thread.
__global__ __launch_bounds__(TSCAT, 8) void scatter_kernel(
    const int* __restrict__ ei,
    const unsigned short* __restrict__ p_ind,
    const unsigned short* __restrict__ p_org,
    const unsigned short* __restrict__ p_ext,
    unsigned* __restrict__ pay,      // [NCOL][CHUNK]
    unsigned* __restrict__ cntoff) { // [NCOL][NB_H]
    const int srcType[NREL] = {0,1,2,0,1,2,0,0,1,2,0,1,2,1};
    const int srcSlot[NREL] = {0,0,0,1,1,1,2,3,2,2,4,3,3,4};
    const int dstSlot[NREL] = {0,1,2,0,1,2,3,3,4,5,4,5,6,6};

    __shared__ unsigned h[NB_H];     // histogram, then cursor (reused)
    __shared__ unsigned stage[CHUNK];
    __shared__ unsigned wsum[16];

    const int t = threadIdx.x;
    const int lane = t & 63, wv = t >> 6; // wv 0..15

    const int cid = blockIdx.x;
    const int r = cid / COLS_PER_REL;
    const int i = cid - r * COLS_PER_REL;
    const int n = (i == COLS_PER_REL - 1) ? LAST_N : CHUNK;
    const int n4 = n >> 2;
    const int* srcp = ei + ((size_t)r * 2 + 0) * E_PER + (size_t)i * CHUNK;
    const int* dstp = ei + ((size_t)r * 2 + 1) * E_PER + (size_t)i * CHUNK;
    const unsigned slotbits = (unsigned)dstSlot[r] << 10;
    const int st = srcType[r];
    const unsigned short* psrc =
        (st == 0) ? p_ind + (size_t)srcSlot[r] * N_IND :
        (st == 1) ? p_org + (size_t)srcSlot[r] * N_ORG :
                    p_ext + (size_t)srcSlot[r] * N_EXT;

    // pass 1: histogram; keep dst values in registers for pass 2
    h[t] = 0u;
    __syncthreads();
    const int4* dst4 = (const int4*)dstp;
    int4 dreg[4];
#pragma unroll
    for (int u = 0; u < 4; ++u) {
        int k = t + u * TSCAT;
        if (k < n4) {
            int4 d = dst4[k];
            dreg[u] = d;
            atomicAdd(&h[d.x >> 10], 1u);
            atomicAdd(&h[d.y >> 10], 1u);
            atomicAdd(&h[d.z >> 10], 1u);
            atomicAdd(&h[d.w >> 10], 1u);
        }
    }
    __syncthreads();

    // exclusive scan over 1024 counters: 1/thread, shfl wave scan + 16 wsums
    unsigned loc0 = h[t];
    unsigned x = loc0;
#pragma unroll
    for (int d = 1; d < 64; d <<= 1) {
        unsigned v = __shfl_up(x, d, 64);
        if (lane >= d) x += v;
    }
    if (lane == 63) wsum[wv] = x;
    __syncthreads();
    unsigned base = x - loc0;
    for (int j = 0; j < wv; ++j) base += wsum[j];
    unsigned* co = cntoff + (size_t)cid * NB_H;
    co[t] = (base << 16) | loc0;
    h[t] = base;          // cursor seed (own slot only)
    __syncthreads();

    // pass 2: gather p, place into LDS stage at sorted positions
    const int4* src4 = (const int4*)srcp;
#pragma unroll
    for (int u = 0; u < 4; ++u) {
        int k = t + u * TSCAT;
        if (k < n4) {
            int4 s = src4[k];
            int4 d = dreg[u];
#pragma unroll
            for (int q = 0; q < 4; ++q) {
                int src = (q == 0) ? s.x : (q == 1) ? s.y : (q == 2) ? s.z : s.w;
                int dst = (q == 0) ? d.x : (q == 1) ? d.y : (q == 2) ? d.z : d.w;
                unsigned pvbits = psrc[src];
                unsigned word = (pvbits << 16) | slotbits | ((unsigned)dst & (BW - 1));
                unsigned pos = atomicAdd(&h[dst >> 10], 1u);
                stage[pos] = word;
            }
        }
    }
    __syncthreads();

    // dense stream-out, 16 B/lane
    uint4* payc4 = (uint4*)(pay + (size_t)cid * CHUNK);
    const uint4* st4 = (const uint4*)stage;
    for (int k = t; k < n4; k += TSCAT) payc4[k] = st4[k];
}

// Transpose cntoff [NCOL][NB_H] -> [NB_H][NCOL] (32x32 tiles).
__global__ __launch_bounds__(256) void transpose_kernel(
    const unsigned* __restrict__ in, unsigned* __restrict__ out) {
    __shared__ unsigned tb[32][33];
    const int c0 = blockIdx.x * 32; // bucket idx
    const int r0 = blockIdx.y * 32; // cid
    const int tx = threadIdx.x & 31, ty = threadIdx.x >> 5;
#pragma unroll
    for (int j = 0; j < 32; j += 8) {
        int r = r0 + ty + j, c = c0 + tx;
        if (r < NCOL && c < NB_H) tb[ty + j][tx] = in[(size_t)r * NB_H + c];
    }
    __syncthreads();
#pragma unroll
    for (int j = 0; j < 32; j += 8) {
        int r = c0 + ty + j, c = r0 + tx;
        if (r < NB_H && c < NCOL) out[(size_t)r * NCOL + c] = tb[tx][ty + j];
    }
}

// Single gather: grid = NBKT, org blocks FIRST (heavier -> no tail).
// One block per (type, bucket); 512 threads, vectorized (uint4) segment
// reads; packed fixed-point LDS accumulate; fused finalize + sigmoid.
__global__ __launch_bounds__(512) void gather_kernel(
    const unsigned* __restrict__ pay,
    const unsigned* __restrict__ cntoffT,
    const float* __restrict__ base_ind,
    const float* __restrict__ base_org,
    float* __restrict__ out) {
    __shared__ unsigned acc[7 * BW];
    const int blk = blockIdx.x; // 0..292 org, 293..1269 ind
    const int t = threadIdx.x;
    for (int j = t; j < 7 * BW; j += 512) acc[j] = 0u;
    __syncthreads();

    const bool isOrg = blk < NB_ORG;
    const int b = isOrg ? blk : blk - NB_ORG;
    const int relsI[7] = {0, 1, 2, 7, 8, 9, 13};
    const int relsO[7] = {3, 4, 5, 6, 10, 11, 12};

#define PROC(w) {                                                        \
        unsigned short hs = (unsigned short)((w) >> 16);                 \
        __half hh;                                                       \
        __builtin_memcpy(&hh, &hs, 2);                                   \
        float pv = __half2float(hh);                                     \
        int fixed = (int)rintf(pv * FIX_SCALE);                          \
        atomicAdd(&acc[(((w) >> 10) & 7u) * BW + ((w) & (BW - 1))],      \
                  (1u << 26) + (unsigned)fixed); }

    const unsigned* row = cntoffT + (size_t)b * NCOL;
    for (int j = t; j < COLS_PER_TYPE; j += 512) {
        int rl = j / COLS_PER_REL;
        int c = j - rl * COLS_PER_REL;
        int cid = (isOrg ? relsO[rl] : relsI[rl]) * COLS_PER_REL + c;
        unsigned co = row[cid];
        unsigned cnt = co & 0xffffu;
        if (!cnt) continue;
        const unsigned* seg = pay + (size_t)cid * CHUNK + (co >> 16);
        // head to 16B alignment
        unsigned e = 0;
        unsigned head = (4u - (((unsigned)(size_t)seg >> 2) & 3u)) & 3u;
        if (head > cnt) head = cnt;
        for (; e < head; ++e) PROC(seg[e]);
        // aligned uint4 body
        unsigned nq = (cnt - e) >> 2;
        const uint4* seg4 = (const uint4*)(seg + e);
        for (unsigned q = 0; q < nq; ++q) {
            uint4 w4 = seg4[q];
            PROC(w4.x); PROC(w4.y); PROC(w4.z); PROC(w4.w);
        }
        // tail
        for (e += nq * 4; e < cnt; ++e) PROC(seg[e]);
    }
#undef PROC
    __syncthreads();

    const int nn = isOrg ? N_ORG : N_IND;
    const float* basep = isOrg ? base_org : base_ind;
    float* outp = isOrg ? out + N_IND : out;
    for (int loc = t; loc < BW; loc += 512) {
        int g = b * BW + loc;
        if (g < nn) {
            float a = basep[g];
#pragma unroll
            for (int k = 0; k < 7; ++k) {
                unsigned w = acc[k * BW + loc];
                int s26 = ((int)(w << 6)) >> 6;         // sign-extend low 26
                unsigned c = (w - (unsigned)s26) >> 26; // exact count
                a += (float)s26 * FIX_INV / fmaxf((float)c, 1.0f);
            }
            outp[g] = 1.0f / (1.0f + __expf(-a));
        }
    }
}

extern "C" void kernel_launch(void* const* d_in, const int* in_sizes, int n_in,
                              void* d_out, int out_size, void* d_ws, size_t ws_size,
                              hipStream_t stream) {
    const float* x_ind = (const float*)d_in[0];
    const float* x_org = (const float*)d_in[1];
    const float* x_ext = (const float*)d_in[2];
    const float* Wl    = (const float*)d_in[3];
    const float* Wr    = (const float*)d_in[4];
    const float* b     = (const float*)d_in[5];
    const int*   ei    = (const int*)d_in[6];
    float* out = (float*)d_out;

    float* ws = (float*)d_ws;
    unsigned* pay      = (unsigned*)(ws + OFF_PAY);
    unsigned* cntoff   = (unsigned*)(ws + OFF_CNTOFF);
    unsigned* cntoffT  = (unsigned*)(ws + OFF_CNTOFF_T);
    __half* p_ind      = (__half*)(ws + OFF_P_IND);
    __half* p_org      = (__half*)(ws + OFF_P_ORG);
    __half* p_ext      = (__half*)(ws + OFF_P_EXT);
    float* base_ind    = ws + OFF_BASE_IND;
    float* base_org    = ws + OFF_BASE_ORG;
    float* wm_ind      = ws + OFF_WM_IND;
    float* wm_org      = ws + OFF_WM_ORG;
    float* wm_ext      = ws + OFF_WM_EXT;
    float* bsum        = ws + OFF_BSUM;

    prep_kernel<<<1, 64, 0, stream>>>(Wl, Wr, b, wm_ind, wm_org, wm_ext, bsum);

    proj_kernel<6, true><<<(N_IND + 255) / 256, 256, 0, stream>>>(
        x_ind, N_IND, wm_ind, p_ind, base_ind, bsum + 0);
    proj_kernel<6, true><<<(N_ORG + 255) / 256, 256, 0, stream>>>(
        x_org, N_ORG, wm_org, p_org, base_org, bsum + 1);
    proj_kernel<4, false><<<(N_EXT + 255) / 256, 256, 0, stream>>>(
        x_ext, N_EXT, wm_ext, p_ext, nullptr, bsum);

    scatter_kernel<<<NCOL, TSCAT, 0, stream>>>(
        ei, (const unsigned short*)p_ind, (const unsigned short*)p_org,
        (const unsigned short*)p_ext, pay, cntoff);

    dim3 tgrid(NB_H / 32, (NCOL + 31) / 32);
    transpose_kernel<<<tgrid, 256, 0, stream>>>(cntoff, cntoffT);

    gather_kernel<<<NBKT, 512, 0, stream>>>(pay, cntoffT, base_ind, base_org, out);
}

// Round 12
// 240.751 us; speedup vs baseline: 1.3458x; 1.0931x over previous
//
#include <hip/hip_runtime.h>
#include <hip/hip_fp16.h>

#define N_IND 1000000
#define N_ORG 300000
#define N_EXT 100000
#define F 64
#define E_PER 1000000
#define NREL 14

#define BW 2048                 // bucket width (nodes), both dst types
#define NB_IND 489              // ceil(N_IND/2048)
#define NB_ORG 147              // ceil(N_ORG/2048)
#define NBKT 636
#define NB_H 512                // hist entries (covers 489)
#define CHUNK 16384             // edges per column
#define COLS_PER_REL 62         // ceil(E_PER/CHUNK)
#define NCOL (NREL * COLS_PER_REL) // 868
#define LAST_N (E_PER - (COLS_PER_REL - 1) * CHUNK) // 576 (divisible by 4)
#define COLS_PER_TYPE (7 * COLS_PER_REL) // 434
#define TSCAT 1024

#define FIX_SCALE 262144.0f            // 2^18
#define FIX_INV   3.814697265625e-6f   // 2^-18

// ---- workspace layout (in 4-byte words) ----
static const size_t OFF_PAY      = 0;          // u32[868][16384] = 14,221,312
static const size_t OFF_CNTOFF   = 14221312;   // u32[868][512] = 444,416
static const size_t OFF_CNTOFF_T = 14665728;   // u32[512][868] = 444,416
static const size_t OFF_P_IND    = 15110144;   // fp16[5][N_IND]
static const size_t OFF_P_ORG    = 17610144;   // fp16[5][N_ORG]
static const size_t OFF_P_EXT    = 18360144;   // fp16[4][N_EXT]
static const size_t OFF_BASE_IND = 18560144;   // f32[N_IND]
static const size_t OFF_BASE_ORG = 19560144;   // f32[N_ORG]
static const size_t OFF_WM_IND   = 19860144;   // 6*64
static const size_t OFF_WM_ORG   = 19860528;   // 6*64
static const size_t OFF_WM_EXT   = 19860912;   // 4*64
static const size_t OFF_BSUM     = 19861168;   // 2
// total ~19.86M words = 79.4 MB

__global__ void prep_kernel(const float* __restrict__ Wl,
                            const float* __restrict__ Wr,
                            const float* __restrict__ b,
                            float* __restrict__ wm_ind,
                            float* __restrict__ wm_org,
                            float* __restrict__ wm_ext,
                            float* __restrict__ bsum) {
    int t = threadIdx.x; // 64 threads
    const int ind_wl[5] = {0, 3, 6, 7, 10};
    const int org_wl[5] = {1, 4, 8, 11, 13};
    const int ext_wl[4] = {2, 5, 9, 12};
    const int ind_r[7]  = {0, 1, 2, 7, 8, 9, 13};
    const int org_r[7]  = {3, 4, 5, 6, 10, 11, 12};
#pragma unroll
    for (int k = 0; k < 5; ++k) wm_ind[k * 64 + t] = Wl[ind_wl[k] * 64 + t];
#pragma unroll
    for (int k = 0; k < 5; ++k) wm_org[k * 64 + t] = Wl[org_wl[k] * 64 + t];
#pragma unroll
    for (int k = 0; k < 4; ++k) wm_ext[k * 64 + t] = Wl[ext_wl[k] * 64 + t];
    float si = 0.f, so = 0.f;
#pragma unroll
    for (int k = 0; k < 7; ++k) {
        si += Wr[ind_r[k] * 64 + t];
        so += Wr[org_r[k] * 64 + t];
    }
    wm_ind[5 * 64 + t] = si;
    wm_org[5 * 64 + t] = so;
    if (t == 0) {
        float bi = 0.f, bo = 0.f;
#pragma unroll
        for (int k = 0; k < 7; ++k) { bi += b[ind_r[k]]; bo += b[org_r[k]]; }
        bsum[0] = bi;
        bsum[1] = bo;
    }
}

// Rank-1 projections -> fp16 p slices (+ f32 base for dst types).
template <int K, bool HASBASE>
__global__ __launch_bounds__(256) void proj_kernel(
    const float* __restrict__ x, int n,
    const float* __restrict__ wm,
    __half* __restrict__ p,
    float* __restrict__ base_out,
    const float* __restrict__ bsum) {
    int i = blockIdx.x * 256 + threadIdx.x;
    if (i >= n) return;
    const float4* xv = (const float4*)(x + (size_t)i * F);
    float acc[K];
#pragma unroll
    for (int k = 0; k < K; ++k) acc[k] = 0.f;
#pragma unroll
    for (int c = 0; c < 16; ++c) {
        float4 v = xv[c];
#pragma unroll
        for (int k = 0; k < K; ++k) {
            const float* w = wm + k * 64 + c * 4;
            acc[k] += v.x * w[0] + v.y * w[1] + v.z * w[2] + v.w * w[3];
        }
    }
    constexpr int NP = HASBASE ? K - 1 : K;
#pragma unroll
    for (int k = 0; k < NP; ++k) p[(size_t)k * n + i] = __float2half_rn(acc[k]);
    if (HASBASE) base_out[i] = acc[K - 1] + bsum[0];
}

// Scatter v8: XCD-swizzled column order (contiguous cid range per XCD ->
// p-slice L2 locality), 1024 threads, CHUNK=16384, 512-entry hist.
// LDS = 64K stage + 2K hist -> 2 blocks/CU, 32 waves/CU.
__global__ __launch_bounds__(TSCAT, 8) void scatter_kernel(
    const int* __restrict__ ei,
    const unsigned short* __restrict__ p_ind,
    const unsigned short* __restrict__ p_org,
    const unsigned short* __restrict__ p_ext,
    unsigned* __restrict__ pay,      // [NCOL][CHUNK]
    unsigned* __restrict__ cntoff) { // [NCOL][NB_H]
    const int srcType[NREL] = {0,1,2,0,1,2,0,0,1,2,0,1,2,1};
    const int srcSlot[NREL] = {0,0,0,1,1,1,2,3,2,2,4,3,3,4};
    const int dstSlot[NREL] = {0,1,2,0,1,2,3,3,4,5,4,5,6,6};

    __shared__ unsigned h[NB_H];     // histogram, then cursor (reused)
    __shared__ unsigned stage[CHUNK];
    __shared__ unsigned wsum[8];

    const int t = threadIdx.x;
    const int lane = t & 63, wv = t >> 6;

    // bijective XCD swizzle (m204): blocks dispatch round-robin over 8 XCDs;
    // give each XCD a contiguous cid range so its L2 holds ~2 p-slices.
    const int q = NCOL >> 3, rem = NCOL & 7;          // 108, 4
    const int xcd = blockIdx.x & 7, idx = blockIdx.x >> 3;
    const int cid = (xcd < rem ? xcd * (q + 1)
                               : rem * (q + 1) + (xcd - rem) * q) + idx;

    const int r = cid / COLS_PER_REL;
    const int i = cid - r * COLS_PER_REL;
    const int n = (i == COLS_PER_REL - 1) ? LAST_N : CHUNK;
    const int n4 = n >> 2;
    const int* srcp = ei + ((size_t)r * 2 + 0) * E_PER + (size_t)i * CHUNK;
    const int* dstp = ei + ((size_t)r * 2 + 1) * E_PER + (size_t)i * CHUNK;
    const unsigned slotbits = (unsigned)dstSlot[r] << 11;
    const int st = srcType[r];
    const unsigned short* psrc =
        (st == 0) ? p_ind + (size_t)srcSlot[r] * N_IND :
        (st == 1) ? p_org + (size_t)srcSlot[r] * N_ORG :
                    p_ext + (size_t)srcSlot[r] * N_EXT;

    // pass 1: histogram; keep dst values in registers for pass 2
    if (t < NB_H) h[t] = 0u;
    __syncthreads();
    const int4* dst4 = (const int4*)dstp;
    int4 dreg[4];
#pragma unroll
    for (int u = 0; u < 4; ++u) {
        int k = t + u * TSCAT;
        if (k < n4) {
            int4 d = dst4[k];
            dreg[u] = d;
            atomicAdd(&h[d.x >> 11], 1u);
            atomicAdd(&h[d.y >> 11], 1u);
            atomicAdd(&h[d.z >> 11], 1u);
            atomicAdd(&h[d.w >> 11], 1u);
        }
    }
    __syncthreads();

    // exclusive scan over 512 counters (threads 0..511): shfl wave scan
    unsigned loc0 = 0, x = 0;
    if (t < NB_H) {
        loc0 = h[t];
        x = loc0;
#pragma unroll
        for (int d = 1; d < 64; d <<= 1) {
            unsigned v = __shfl_up(x, d, 64);
            if (lane >= d) x += v;
        }
        if (lane == 63) wsum[wv] = x;
    }
    __syncthreads();
    if (t < NB_H) {
        unsigned base = x - loc0;
        for (int j = 0; j < wv; ++j) base += wsum[j];
        cntoff[(size_t)cid * NB_H + t] = (base << 16) | loc0;
        h[t] = base;          // cursor seed (own slot only)
    }
    __syncthreads();

    // pass 2: gather p, place into LDS stage at sorted positions
    const int4* src4 = (const int4*)srcp;
#pragma unroll
    for (int u = 0; u < 4; ++u) {
        int k = t + u * TSCAT;
        if (k < n4) {
            int4 s = src4[k];
            int4 d = dreg[u];
#pragma unroll
            for (int qd = 0; qd < 4; ++qd) {
                int src = (qd == 0) ? s.x : (qd == 1) ? s.y : (qd == 2) ? s.z : s.w;
                int dst = (qd == 0) ? d.x : (qd == 1) ? d.y : (qd == 2) ? d.z : d.w;
                unsigned pvbits = psrc[src];
                unsigned word = (pvbits << 16) | slotbits | ((unsigned)dst & (BW - 1));
                unsigned pos = atomicAdd(&h[dst >> 11], 1u);
                stage[pos] = word;
            }
        }
    }
    __syncthreads();

    // dense stream-out, 16 B/lane
    uint4* payc4 = (uint4*)(pay + (size_t)cid * CHUNK);
    const uint4* st4 = (const uint4*)stage;
    for (int k = t; k < n4; k += TSCAT) payc4[k] = st4[k];
}

// Transpose cntoff [NCOL][NB_H] -> [NB_H][NCOL] (32x32 tiles).
__global__ __launch_bounds__(256) void transpose_kernel(
    const unsigned* __restrict__ in, unsigned* __restrict__ out) {
    __shared__ unsigned tb[32][33];
    const int c0 = blockIdx.x * 32; // bucket idx
    const int r0 = blockIdx.y * 32; // cid
    const int tx = threadIdx.x & 31, ty = threadIdx.x >> 5;
#pragma unroll
    for (int j = 0; j < 32; j += 8) {
        int r = r0 + ty + j, c = c0 + tx;
        if (r < NCOL && c < NB_H) tb[ty + j][tx] = in[(size_t)r * NB_H + c];
    }
    __syncthreads();
#pragma unroll
    for (int j = 0; j < 32; j += 8) {
        int r = c0 + ty + j, c = r0 + tx;
        if (r < NB_H && c < NCOL) out[(size_t)r * NCOL + c] = tb[tx][ty + j];
    }
}

// Single gather: grid = NBKT, org blocks FIRST (heavier -> no tail).
// 512 threads, 2048-node buckets (56 KB LDS acc), vectorized uint4 segment
// reads, packed fixed-point LDS accumulate, fused finalize + sigmoid.
__global__ __launch_bounds__(512) void gather_kernel(
    const unsigned* __restrict__ pay,
    const unsigned* __restrict__ cntoffT,
    const float* __restrict__ base_ind,
    const float* __restrict__ base_org,
    float* __restrict__ out) {
    __shared__ unsigned acc[7 * BW];
    const int blk = blockIdx.x; // 0..146 org, 147..635 ind
    const int t = threadIdx.x;
    for (int j = t; j < 7 * BW; j += 512) acc[j] = 0u;
    __syncthreads();

    const bool isOrg = blk < NB_ORG;
    const int b = isOrg ? blk : blk - NB_ORG;
    const int relsI[7] = {0, 1, 2, 7, 8, 9, 13};
    const int relsO[7] = {3, 4, 5, 6, 10, 11, 12};

#define PROC(w) {                                                        \
        unsigned short hs = (unsigned short)((w) >> 16);                 \
        __half hh;                                                       \
        __builtin_memcpy(&hh, &hs, 2);                                   \
        float pv = __half2float(hh);                                     \
        int fixed = (int)rintf(pv * FIX_SCALE);                          \
        atomicAdd(&acc[(((w) >> 11) & 7u) * BW + ((w) & (BW - 1))],      \
                  (1u << 26) + (unsigned)fixed); }

    const unsigned* row = cntoffT + (size_t)b * NCOL;
    for (int j = t; j < COLS_PER_TYPE; j += 512) {
        int rl = j / COLS_PER_REL;
        int c = j - rl * COLS_PER_REL;
        int cid = (isOrg ? relsO[rl] : relsI[rl]) * COLS_PER_REL + c;
        unsigned co = row[cid];
        unsigned cnt = co & 0xffffu;
        if (!cnt) continue;
        const unsigned* seg = pay + (size_t)cid * CHUNK + (co >> 16);
        // head to 16B alignment
        unsigned e = 0;
        unsigned head = (4u - (((unsigned)(size_t)seg >> 2) & 3u)) & 3u;
        if (head > cnt) head = cnt;
        for (; e < head; ++e) PROC(seg[e]);
        // aligned uint4 body
        unsigned nq = (cnt - e) >> 2;
        const uint4* seg4 = (const uint4*)(seg + e);
        for (unsigned qq = 0; qq < nq; ++qq) {
            uint4 w4 = seg4[qq];
            PROC(w4.x); PROC(w4.y); PROC(w4.z); PROC(w4.w);
        }
        // tail
        for (e += nq * 4; e < cnt; ++e) PROC(seg[e]);
    }
#undef PROC
    __syncthreads();

    const int nn = isOrg ? N_ORG : N_IND;
    const float* basep = isOrg ? base_org : base_ind;
    float* outp = isOrg ? out + N_IND : out;
    for (int loc = t; loc < BW; loc += 512) {
        int g = b * BW + loc;
        if (g < nn) {
            float a = basep[g];
#pragma unroll
            for (int k = 0; k < 7; ++k) {
                unsigned w = acc[k * BW + loc];
                int s26 = ((int)(w << 6)) >> 6;         // sign-extend low 26
                unsigned c = (w - (unsigned)s26) >> 26; // exact count
                a += (float)s26 * FIX_INV / fmaxf((float)c, 1.0f);
            }
            outp[g] = 1.0f / (1.0f + __expf(-a));
        }
    }
}

extern "C" void kernel_launch(void* const* d_in, const int* in_sizes, int n_in,
                              void* d_out, int out_size, void* d_ws, size_t ws_size,
                              hipStream_t stream) {
    const float* x_ind = (const float*)d_in[0];
    const float* x_org = (const float*)d_in[1];
    const float* x_ext = (const float*)d_in[2];
    const float* Wl    = (const float*)d_in[3];
    const float* Wr    = (const float*)d_in[4];
    const float* b     = (const float*)d_in[5];
    const int*   ei    = (const int*)d_in[6];
    float* out = (float*)d_out;

    float* ws = (float*)d_ws;
    unsigned* pay      = (unsigned*)(ws + OFF_PAY);
    unsigned* cntoff   = (unsigned*)(ws + OFF_CNTOFF);
    unsigned* cntoffT  = (unsigned*)(ws + OFF_CNTOFF_T);
    __half* p_ind      = (__half*)(ws + OFF_P_IND);
    __half* p_org      = (__half*)(ws + OFF_P_ORG);
    __half* p_ext      = (__half*)(ws + OFF_P_EXT);
    float* base_ind    = ws + OFF_BASE_IND;
    float* base_org    = ws + OFF_BASE_ORG;
    float* wm_ind      = ws + OFF_WM_IND;
    float* wm_org      = ws + OFF_WM_ORG;
    float* wm_ext      = ws + OFF_WM_EXT;
    float* bsum        = ws + OFF_BSUM;

    prep_kernel<<<1, 64, 0, stream>>>(Wl, Wr, b, wm_ind, wm_org, wm_ext, bsum);

    proj_kernel<6, true><<<(N_IND + 255) / 256, 256, 0, stream>>>(
        x_ind, N_IND, wm_ind, p_ind, base_ind, bsum + 0);
    proj_kernel<6, true><<<(N_ORG + 255) / 256, 256, 0, stream>>>(
        x_org, N_ORG, wm_org, p_org, base_org, bsum + 1);
    proj_kernel<4, false><<<(N_EXT + 255) / 256, 256, 0, stream>>>(
        x_ext, N_EXT, wm_ext, p_ext, nullptr, bsum);

    scatter_kernel<<<NCOL, TSCAT, 0, stream>>>(
        ei, (const unsigned short*)p_ind, (const unsigned short*)p_org,
        (const unsigned short*)p_ext, pay, cntoff);

    dim3 tgrid(NB_H / 32, (NCOL + 31) / 32);
    transpose_kernel<<<tgrid, 256, 0, stream>>>(cntoff, cntoffT);

    gather_kernel<<<NBKT, 512, 0, stream>>>(pay, cntoffT, base_ind, base_org, out);
}